// Round 3
// baseline (326.776 us; speedup 1.0000x reference)
//
#include <hip/hip_runtime.h>

#define NQ 12
#define DIM 4096

// One wave (64 threads) per batch element. 64 float2 amplitudes per thread.
// Layout [N]: amplitude a = (r<<6)|L  (bits 0..5 = lane L, bits 6..11 = reg r)
// Layout [T]: amplitude a = (L<<6)|r  (bits 0..5 = reg r, bits 6..11 = lane L)
// Qubit q lives at amplitude bit (11-q).

using F2 = float2;

__device__ __forceinline__ void build_u(float tx, float ty, float tz, float u[8]) {
    float sx = sinf(0.5f*tx), cx = cosf(0.5f*tx);
    float sy = sinf(0.5f*ty), cy = cosf(0.5f*ty);
    float sz = sinf(0.5f*tz), cz = cosf(0.5f*tz);
    // A = Ry*Rx
    float A00r = cy*cx, A00i =  sy*sx;
    float A01r = -sy*cx, A01i = -cy*sx;
    float A10r =  sy*cx, A10i = -cy*sx;
    float A11r =  cy*cx, A11i = -sy*sx;
    // U = Rz*A: row0 *= (cz - i sz), row1 *= (cz + i sz)   [verified: round-1 passed]
    u[0] = cz*A00r + sz*A00i;  u[1] = cz*A00i - sz*A00r;
    u[2] = cz*A01r + sz*A01i;  u[3] = cz*A01i - sz*A01r;
    u[4] = cz*A10r - sz*A10i;  u[5] = cz*A10i + sz*A10r;
    u[6] = cz*A11r - sz*A11i;  u[7] = cz*A11i + sz*A11r;
}

// 2x2 complex gate on register-bit M pairs (compile-time mask => guards fold away)
template<int M>
__device__ __forceinline__ void reg_1q(F2* amp, const float u[8]) {
#pragma unroll
    for (int r0 = 0; r0 < 64; ++r0) {
        if (r0 & M) continue;
        const int r1 = r0 + M;
        F2 a0 = amp[r0], a1 = amp[r1];
        amp[r0].x = u[0]*a0.x - u[1]*a0.y + u[2]*a1.x - u[3]*a1.y;
        amp[r0].y = u[0]*a0.y + u[1]*a0.x + u[2]*a1.y + u[3]*a1.x;
        amp[r1].x = u[4]*a0.x - u[5]*a0.y + u[6]*a1.x - u[7]*a1.y;
        amp[r1].y = u[4]*a0.y + u[5]*a0.x + u[6]*a1.y + u[7]*a1.x;
    }
}

// CRX: control reg bit MC (=1), target reg bit MT. RX on target: a0'=c a0 - i s a1
template<int MC, int MT>
__device__ __forceinline__ void reg_crx(F2* amp, float cc, float ss) {
#pragma unroll
    for (int r0 = 0; r0 < 64; ++r0) {
        if (!(r0 & MC) || (r0 & MT)) continue;
        const int r1 = r0 + MT;
        F2 a0 = amp[r0], a1 = amp[r1];
        amp[r0] = make_float2(cc*a0.x + ss*a1.y, cc*a0.y - ss*a1.x);
        amp[r1] = make_float2(ss*a0.y + cc*a1.x, -ss*a0.x + cc*a1.y);
    }
}

// CRX with lane-bit control folded into per-thread coefficients (c2,s2)=(1,0) if inactive
template<int MT>
__device__ __forceinline__ void fold_crx(F2* amp, float c2, float s2) {
#pragma unroll
    for (int r0 = 0; r0 < 64; ++r0) {
        if (r0 & MT) continue;
        const int r1 = r0 + MT;
        F2 a0 = amp[r0], a1 = amp[r1];
        amp[r0] = make_float2(c2*a0.x + s2*a1.y, c2*a0.y - s2*a1.x);
        amp[r1] = make_float2(s2*a0.y + c2*a1.x, -s2*a0.x + c2*a1.y);
    }
}

// <X_q>,<Y_q>,<Z_q> partials over this thread's reg pairs, folded into acc via W
template<int M>
__device__ __forceinline__ void expval_acc(const F2* amp, const float* __restrict__ W,
                                           int q, float* acc) {
    float xr = 0.f, xi = 0.f, zz = 0.f;
#pragma unroll
    for (int r0 = 0; r0 < 64; ++r0) {
        if (r0 & M) continue;
        const int r1 = r0 + M;
        F2 a0 = amp[r0], a1 = amp[r1];
        zz += a0.x*a0.x + a0.y*a0.y - a1.x*a1.x - a1.y*a1.y;
        xr += a0.x*a1.x + a0.y*a1.y;   // Re(conj(a0)*a1)
        xi += a0.x*a1.y - a0.y*a1.x;   // Im(conj(a0)*a1)
    }
    xr *= 2.f; xi *= 2.f;              // X=2ReS, Y=2ImS; pairs disjoint across lanes
#pragma unroll
    for (int c = 0; c < 10; ++c)
        acc[c] += W[c*36 + q]*xr + W[c*36 + 12 + q]*xi + W[c*36 + 24 + q]*zz;
}

// Transpose [N]<->[T] through LDS. XOR swizzle keeps both phases <=2-way (free).
// __syncthreads() guarantees cross-lane store->load ordering (single wave: cheap).
__device__ __forceinline__ void xpose(F2* amp, F2* lds, int L, bool NtoT) {
#pragma unroll
    for (int r = 0; r < 64; ++r) {
        int a = NtoT ? ((r << 6) | L) : ((L << 6) | r);       // current layout
        lds[(a & ~63) | ((a ^ (a >> 6)) & 63)] = amp[r];
    }
    __syncthreads();
#pragma unroll
    for (int r = 0; r < 64; ++r) {
        int a = NtoT ? ((L << 6) | r) : ((r << 6) | L);       // next layout
        amp[r] = lds[(a & ~63) | ((a ^ (a >> 6)) & 63)];
    }
    __syncthreads();
}

#define L0_1Q(q, M)  do { build_u(ang[q], ang[12+(q)], ang[24+(q)], u); reg_1q<M>(amp, u); } while(0)
#define L1_1Q(q, M)  do { build_u(ang[48+(q)], ang[60+(q)], ang[72+(q)], u); reg_1q<M>(amp, u); } while(0)
#define L0_CRX(c, MC, MT) do { ss = sinf(0.5f*ang[36+(c)]); cc = cosf(0.5f*ang[36+(c)]); reg_crx<MC, MT>(amp, cc, ss); } while(0)
#define L1_CRX(c, MC, MT) do { ss = sinf(0.5f*ang[95-(c)]); cc = cosf(0.5f*ang[95-(c)]); reg_crx<MC, MT>(amp, cc, ss); } while(0)
#define L0_FOLD(c, MT) do { ss = sinf(0.5f*ang[36+(c)]); cc = cosf(0.5f*ang[36+(c)]); fold_crx<MT>(amp, act ? cc : 1.f, act ? ss : 0.f); } while(0)
#define L1_FOLD(c, MT) do { ss = sinf(0.5f*ang[95-(c)]); cc = cosf(0.5f*ang[95-(c)]); fold_crx<MT>(amp, act ? cc : 1.f, act ? ss : 0.f); } while(0)

__global__ __launch_bounds__(64)
void qsim_kernel(const float* __restrict__ sv,      // [B, 4096]
                 const float* __restrict__ ang,     // [96]
                 const float* __restrict__ W,       // [10, 36]
                 const float* __restrict__ bvec,    // [10]
                 float* __restrict__ out)           // [B, 10]
{
    __shared__ F2 lds[DIM];                         // 32 KB
    const int L = threadIdx.x;
    const int b = blockIdx.x;
    const int act = L & 1;   // both folded gates have control on amplitude-bit 0 = lane bit 0

    F2 amp[64];
    const float* svb = sv + (size_t)b * DIM;
#pragma unroll
    for (int r = 0; r < 64; ++r)
        amp[r] = make_float2(svb[(r << 6) | L], 0.f);   // [N]

    float u[8], cc, ss;

    // ---- P1 [N]: L0 1q on qubits 0..5 (reg bit 5-q); L0 ring (0,1)..(4,5) ----
    L0_1Q(0, 32); L0_1Q(1, 16); L0_1Q(2, 8); L0_1Q(3, 4); L0_1Q(4, 2); L0_1Q(5, 1);
    L0_CRX(0, 32, 16); L0_CRX(1, 16, 8); L0_CRX(2, 8, 4); L0_CRX(3, 4, 2); L0_CRX(4, 2, 1);
    xpose(amp, lds, L, true);

    // ---- P2 [T]: L0 1q qubits 6..11 (reg bit 11-q); L0 ring (5,6)..(10,11);
    //              L1 1q qubits 6..10 (commute past L0 (11,0): disjoint qubits) ----
    L0_1Q(6, 32); L0_1Q(7, 16); L0_1Q(8, 8); L0_1Q(9, 4); L0_1Q(10, 2); L0_1Q(11, 1);
    L0_FOLD(5, 32);                      // ctrl qubit5=bit6=lane bit0, tgt qubit6=reg bit5
    L0_CRX(6, 32, 16); L0_CRX(7, 16, 8); L0_CRX(8, 8, 4); L0_CRX(9, 4, 2); L0_CRX(10, 2, 1);
    L1_1Q(6, 32); L1_1Q(7, 16); L1_1Q(8, 8); L1_1Q(9, 4); L1_1Q(10, 2);
    xpose(amp, lds, L, false);

    // ---- P3 [N]: L0 ring (11,0) (ctrl bit0=lane, tgt qubit0=reg bit5); L1 1q qubits 0..5 ----
    L0_FOLD(11, 32);
    L1_1Q(0, 32); L1_1Q(1, 16); L1_1Q(2, 8); L1_1Q(3, 4); L1_1Q(4, 2); L1_1Q(5, 1);
    xpose(amp, lds, L, true);

    // ---- P4 [T]: L1 1q qubit 11 (bit0 = reg bit 0) ----
    L1_1Q(11, 1);
    xpose(amp, lds, L, false);

    // ---- P5 [N]: L1 ring (11,0) ----
    L1_FOLD(11, 32);
    xpose(amp, lds, L, true);

    float acc[10];
#pragma unroll
    for (int c = 0; c < 10; ++c) acc[c] = 0.f;

    // ---- P6 [T]: L1 ring (10,11),(9,10),(8,9),(7,8),(6,7),(5,6);
    //              expvals qubits 6..11 (их last gates done; rest touch qubits 0..5 only) ----
    L1_CRX(10, 2, 1); L1_CRX(9, 4, 2); L1_CRX(8, 8, 4); L1_CRX(7, 16, 8); L1_CRX(6, 32, 16);
    L1_FOLD(5, 32);
    expval_acc<32>(amp, W, 6, acc); expval_acc<16>(amp, W, 7, acc);
    expval_acc<8>(amp, W, 8, acc);  expval_acc<4>(amp, W, 9, acc);
    expval_acc<2>(amp, W, 10, acc); expval_acc<1>(amp, W, 11, acc);
    xpose(amp, lds, L, false);

    // ---- P7 [N]: L1 ring (4,5),(3,4),(2,3),(1,2),(0,1); expvals qubits 0..5 ----
    L1_CRX(4, 2, 1); L1_CRX(3, 4, 2); L1_CRX(2, 8, 4); L1_CRX(1, 16, 8); L1_CRX(0, 32, 16);
    expval_acc<32>(amp, W, 0, acc); expval_acc<16>(amp, W, 1, acc);
    expval_acc<8>(amp, W, 2, acc);  expval_acc<4>(amp, W, 3, acc);
    expval_acc<2>(amp, W, 4, acc);  expval_acc<1>(amp, W, 5, acc);

    // ---- reduce 10 partials across the wave (proven round-1 pattern), bias, store ----
#pragma unroll
    for (int c = 0; c < 10; ++c) {
#pragma unroll
        for (int off = 32; off; off >>= 1) acc[c] += __shfl_xor(acc[c], off);
        acc[c] += bvec[c];
    }
#pragma unroll
    for (int c = 0; c < 10; ++c)
        if (L == c) out[(size_t)b * 10 + c] = acc[c];
}

extern "C" void kernel_launch(void* const* d_in, const int* in_sizes, int n_in,
                              void* d_out, int out_size, void* d_ws, size_t ws_size,
                              hipStream_t stream) {
    const float* sv     = (const float*)d_in[0];
    const float* angles = (const float*)d_in[1];
    const float* W      = (const float*)d_in[2];
    const float* bvec   = (const float*)d_in[3];
    float* out = (float*)d_out;
    int batch = in_sizes[0] / DIM;   // 2048
    qsim_kernel<<<batch, 64, 0, stream>>>(sv, angles, W, bvec, out);
}